// Round 1
// baseline (226.876 us; speedup 1.0000x reference)
//
#include <hip/hip_runtime.h>
#include <hip/hip_bf16.h>

// HypConvHyperboloid: B=32,H=64,W=64, C_IN=65, 3x3 edge-pad conv -> HCat(577) -> Lorentz FC(255) -> time restore
// M = 131072 pixels, K = 576 (spatial, bf16 MFMA) + 1 (t_cat, fp32 rank-1 in epilogue), N = 255 (pad 256)

#define CLAMP63(v) ((v) < 0 ? 0 : ((v) > 63 ? 63 : (v)))

typedef __attribute__((ext_vector_type(8))) short short8;   // 8 bf16 = 4 VGPRs (A/B frag)
typedef __attribute__((ext_vector_type(4))) float floatx4;  // C/D frag

__device__ __forceinline__ void gl2lds16(const void* g, void* l) {
  __builtin_amdgcn_global_load_lds(
      (const __attribute__((address_space(1))) void*)g,
      (__attribute__((address_space(3))) void*)l, 16, 0, 0);
}

// ---- prep: x spatial -> bf16 (pixel-major, 64 chans contiguous), tsq = t^2
__global__ void prep_x(const float* __restrict__ x, __hip_bfloat16* __restrict__ xs,
                       float* __restrict__ tsq) {
  int idx = blockIdx.x * 256 + threadIdx.x;   // 131072*64 total
  int p = idx >> 6, c = idx & 63;
  xs[idx] = __float2bfloat16(x[p * 65 + 1 + c]);
  if (c == 0) { float t = x[p * 65]; tsq[p] = t * t; }
}

// ---- prep: t_cat[p] = sqrt(sum_{3x3 clamped} t^2 - 8)
__global__ void prep_tcat(const float* __restrict__ tsq, float* __restrict__ tcat) {
  int p = blockIdx.x * 256 + threadIdx.x;     // 131072 total
  int xx = p & 63, yy = (p >> 6) & 63, bb = p >> 12;
  float s = 0.f;
#pragma unroll
  for (int dy = -1; dy <= 1; ++dy) {
    int y2 = CLAMP63(yy + dy);
#pragma unroll
    for (int dx = -1; dx <= 1; ++dx) {
      int x2 = CLAMP63(xx + dx);
      s += tsq[(bb * 64 + y2) * 64 + x2];
    }
  }
  tcat[p] = sqrtf(s - 8.0f);
}

// ---- prep: W spatial cols -> bf16 n-major [256][576] (row 255 zero); W col0 + b -> fp32 padded
__global__ void prep_w(const float* __restrict__ W, const float* __restrict__ b,
                       __hip_bfloat16* __restrict__ Wb, float* __restrict__ Wt0,
                       float* __restrict__ bp) {
  int n = blockIdx.x;  // 256
  for (int k = threadIdx.x; k < 576; k += 256) {
    float v = (n < 255) ? W[n * 577 + 1 + k] : 0.f;
    Wb[n * 576 + k] = __float2bfloat16(v);
  }
  if (threadIdx.x == 0) {
    Wt0[n] = (n < 255) ? W[n * 577] : 0.f;
    bp[n] = (n < 255) ? b[n] : 0.f;
  }
}

// ---- main: tile M=128 x N=256, BK=32, 18 K-iters. 4 waves, each 64(M)x128(N) = 4x8 16x16 frags.
__launch_bounds__(256, 2)
__global__ void hypconv_main(const __hip_bfloat16* __restrict__ xs,
                             const __hip_bfloat16* __restrict__ Wb,
                             const float* __restrict__ Wt0,
                             const float* __restrict__ bp,
                             const float* __restrict__ tcat,
                             float* __restrict__ out) {
  __shared__ ushort Ab[128 * 32];   // [m][k] rows of 64 B (global_load_lds forces no pad)
  __shared__ ushort Bb[256 * 32];   // [n][k] rows of 64 B
  __shared__ float sq_lds[256];     // [n_half][m]

  const int tid = threadIdx.x;
  const int w = tid >> 6;
  const int lane = tid & 63;
  const int quad = lane >> 4;
  const int ln = lane & 15;
  const int pix_base = blockIdx.x * 128;

  // A staging: 2 chunks/thread, chunk i = (w*2+q)*64+lane -> m=i>>2, kgroup=i&3
  int a_kg[2], a_bx[2], a_by[2], a_bb[2];
#pragma unroll
  for (int q = 0; q < 2; ++q) {
    int i = (w * 2 + q) * 64 + lane;
    a_kg[q] = i & 3;
    int pix = pix_base + (i >> 2);
    a_bx[q] = pix & 63; a_by[q] = (pix >> 6) & 63; a_bb[q] = pix >> 12;
  }
  // B staging: 4 chunks/thread, chunk i = (w*4+p)*64+lane -> n=i>>2, kgroup=i&3
  int b_n[4], b_kg[4];
#pragma unroll
  for (int p = 0; p < 4; ++p) {
    int i = (w * 4 + p) * 64 + lane;
    b_n[p] = i >> 2; b_kg[p] = i & 3;
  }

  const int m_off = (w >> 1) * 64;   // waves 0,1: m 0..63 ; waves 2,3: m 64..127
  const int n_off = (w & 1) * 128;   // waves 0,2: n 0..127; waves 1,3: n 128..255

  floatx4 acc[4][8];
#pragma unroll
  for (int mf = 0; mf < 4; ++mf)
#pragma unroll
    for (int nf = 0; nf < 8; ++nf)
      acc[mf][nf] = (floatx4){0.f, 0.f, 0.f, 0.f};

  for (int it = 0; it < 18; ++it) {       // k = it*32 .. +32 ; neighbor = it>>1, chans (it&1)*32..
    __syncthreads();                      // prev iter's frag reads done before overwrite
    const int nbr = it >> 1;
    const int dy = nbr / 3 - 1, dx = nbr % 3 - 1;
    const int c0 = (it & 1) * 32;
#pragma unroll
    for (int q = 0; q < 2; ++q) {
      int y2 = CLAMP63(a_by[q] + dy);
      int x2 = CLAMP63(a_bx[q] + dx);
      const __hip_bfloat16* src =
          xs + (size_t)((a_bb[q] * 64 + y2) * 64 + x2) * 64 + c0 + a_kg[q] * 8;
      gl2lds16(src, &Ab[(w * 2 + q) * 512]);
    }
#pragma unroll
    for (int p = 0; p < 4; ++p) {
      const __hip_bfloat16* src = Wb + b_n[p] * 576 + it * 32 + b_kg[p] * 8;
      gl2lds16(src, &Bb[(w * 4 + p) * 512]);
    }
    __syncthreads();                      // drains vmcnt -> tiles visible

    short8 af[4], bfr[8];
#pragma unroll
    for (int mf = 0; mf < 4; ++mf)
      af[mf] = *(const short8*)&Ab[(m_off + mf * 16 + ln) * 32 + quad * 8];
#pragma unroll
    for (int nf = 0; nf < 8; ++nf)
      bfr[nf] = *(const short8*)&Bb[(n_off + nf * 16 + ln) * 32 + quad * 8];
#pragma unroll
    for (int mf = 0; mf < 4; ++mf)
#pragma unroll
      for (int nf = 0; nf < 8; ++nf)
        acc[mf][nf] = __builtin_amdgcn_mfma_f32_16x16x32_bf16(af[mf], bfr[nf], acc[mf][nf], 0, 0, 0);
  }

  // ---- epilogue: z = acc + b[n] + t_cat[m]*W0[n] (fp32 rank-1); out[.,1+n]=z; t_out=sqrt(1+sum z^2)
  float wn[8], bnv[8];
#pragma unroll
  for (int nf = 0; nf < 8; ++nf) {
    int n = n_off + nf * 16 + ln;
    wn[nf] = Wt0[n];
    bnv[nf] = bp[n];
  }
  float tc[4][4];
#pragma unroll
  for (int mf = 0; mf < 4; ++mf)
#pragma unroll
    for (int r = 0; r < 4; ++r)
      tc[mf][r] = tcat[pix_base + m_off + mf * 16 + quad * 4 + r];

  float sq[4][4];
#pragma unroll
  for (int mf = 0; mf < 4; ++mf) {
#pragma unroll
    for (int r = 0; r < 4; ++r) {
      int m = m_off + mf * 16 + quad * 4 + r;
      size_t orow = (size_t)(pix_base + m) * 256;
      float s = 0.f;
#pragma unroll
      for (int nf = 0; nf < 8; ++nf) {
        int n = n_off + nf * 16 + ln;
        float z = acc[mf][nf][r] + bnv[nf] + tc[mf][r] * wn[nf];
        s += z * z;
        if (n < 255) out[orow + 1 + n] = z;  // n=255 is zero-padding, skipped
      }
      sq[mf][r] = s;
    }
  }

  // reduce sum(z^2) over the 16 lanes sharing m (xor masks stay inside the 16-group)
#pragma unroll
  for (int mf = 0; mf < 4; ++mf)
#pragma unroll
    for (int r = 0; r < 4; ++r) {
      float s = sq[mf][r];
      s += __shfl_xor(s, 1, 64);
      s += __shfl_xor(s, 2, 64);
      s += __shfl_xor(s, 4, 64);
      s += __shfl_xor(s, 8, 64);
      if (ln == 0)
        sq_lds[(w & 1) * 128 + m_off + mf * 16 + quad * 4 + r] = s;
    }
  __syncthreads();
  if (tid < 128) {
    float s = sq_lds[tid] + sq_lds[128 + tid];  // combine the two n-halves
    out[(size_t)(pix_base + tid) * 256] = sqrtf(1.0f + s);
  }
}

extern "C" void kernel_launch(void* const* d_in, const int* in_sizes, int n_in,
                              void* d_out, int out_size, void* d_ws, size_t ws_size,
                              hipStream_t stream) {
  const float* x = (const float*)d_in[0];   // (32,64,64,65)
  const float* W = (const float*)d_in[1];   // (255,577)
  const float* b = (const float*)d_in[2];   // (255,)
  float* out = (float*)d_out;               // (32,64,64,256)
  char* ws = (char*)d_ws;

  // workspace layout (16B-aligned offsets), total ~18.1 MB
  __hip_bfloat16* xs  = (__hip_bfloat16*)(ws);                // 131072*64 bf16 = 16,777,216 B
  __hip_bfloat16* Wb  = (__hip_bfloat16*)(ws + 16777216);     // 256*576 bf16   =    294,912 B
  float*          Wt0 = (float*)(ws + 17072128);              // 256 f32
  float*          bp  = (float*)(ws + 17073152);              // 256 f32
  float*          tsq = (float*)(ws + 17074176);              // 131072 f32
  float*          tcat= (float*)(ws + 17598464);              // 131072 f32

  prep_x   <<<32768, 256, 0, stream>>>(x, xs, tsq);
  prep_w   <<<256,   256, 0, stream>>>(W, b, Wb, Wt0, bp);
  prep_tcat<<<512,   256, 0, stream>>>(tsq, tcat);
  hypconv_main<<<1024, 256, 0, stream>>>(xs, Wb, Wt0, bp, tcat, out);
}

// Round 4
// 224.822 us; speedup vs baseline: 1.0091x; 1.0091x over previous
//
#include <hip/hip_runtime.h>
#include <hip/hip_bf16.h>

// HypConvHyperboloid: B=32,H=64,W=64, C_IN=65, 3x3 edge-pad conv -> HCat(577) -> Lorentz FC(255) -> time restore
// M = 131072 pixels, K = 576 (bf16 MFMA) + 1 (t_cat fp32 rank-1 in epilogue), N = 255 (pad 256)
// Round 4 == round 2 design, lambda manually inlined (de-risk), B-staging addrs hoisted.
// dbuf prefetch K-loop, [kg][row] conflict-free LDS, LDS-staged coalesced epilogue.

#define CLAMP63(v) ((v) < 0 ? 0 : ((v) > 63 ? 63 : (v)))

typedef __attribute__((ext_vector_type(8))) short short8;   // 8 bf16 = 4 VGPRs
typedef __attribute__((ext_vector_type(4))) float floatx4;  // C/D frag

__device__ __forceinline__ void gl2lds16(const void* g, void* l) {
  __builtin_amdgcn_global_load_lds(
      (const __attribute__((address_space(1))) void*)g,
      (__attribute__((address_space(3))) void*)l, 16, 0, 0);
}

// ---- prep: x spatial -> bf16 pixel-major [pix][64], 16B stores
__global__ void prep_x(const float* __restrict__ x, __hip_bfloat16* __restrict__ xs) {
  int idx = blockIdx.x * 256 + threadIdx.x;   // 1048576 = 131072 pix * 8 groups
  int p = idx >> 3, g = idx & 7;
  const float* src = x + (size_t)p * 65 + 1 + g * 8;
  __align__(16) __hip_bfloat16 tmp[8];
#pragma unroll
  for (int i = 0; i < 8; ++i) tmp[i] = __float2bfloat16(src[i]);
  *(short8*)(xs + (size_t)idx * 8) = *(const short8*)tmp;
}

// ---- prep: W spatial cols -> bf16 n-major [256][576] (row 255 zero); W col0 + b -> fp32 padded
__global__ void prep_w(const float* __restrict__ W, const float* __restrict__ b,
                       __hip_bfloat16* __restrict__ Wb, float* __restrict__ Wt0,
                       float* __restrict__ bp) {
  int n = blockIdx.x;  // 256
  for (int k = threadIdx.x; k < 576; k += 256)
    Wb[n * 576 + k] = __float2bfloat16((n < 255) ? W[n * 577 + 1 + k] : 0.f);
  if (threadIdx.x == 0) {
    Wt0[n] = (n < 255) ? W[n * 577] : 0.f;
    bp[n]  = (n < 255) ? b[n] : 0.f;
  }
}

// staging for one iteration, expanded inline (no lambda)
#define STAGE(IT, BUF)                                                          \
  do {                                                                          \
    const int nbr_ = (IT) >> 1;                                                 \
    const int dy_ = nbr_ / 3 - 1, dx_ = nbr_ % 3 - 1;                           \
    const int c0_ = ((IT) & 1) * 32;                                            \
    _Pragma("unroll")                                                           \
    for (int q = 0; q < 2; ++q) {                                               \
      int y2 = CLAMP63(a_by[q] + dy_);                                          \
      int x2 = CLAMP63(a_bx[q] + dx_);                                          \
      const __hip_bfloat16* src =                                               \
          xs + (size_t)((a_bb[q] * 64 + y2) * 64 + x2) * 64 + c0_ + w * 8;      \
      gl2lds16(src, Ab + (BUF) * 4096 + (w * 2 + q) * 512);                     \
    }                                                                           \
    _Pragma("unroll")                                                           \
    for (int p = 0; p < 4; ++p)                                                 \
      gl2lds16(b_src[p] + (IT) * 32, Bb + (BUF) * 8192 + (w * 4 + p) * 512);    \
  } while (0)

// ---- main: M=128 x N=256 per block, BK=32, 18 iters, 4 waves (each 64x128), dbuf LDS.
// LDS A layout: slot = kg*128 + m (16B slots)  -> frag read addr = const + ln*16 (2-way, free)
// LDS B layout: slot = kg*256 + n
__launch_bounds__(256, 2)
__global__ void hypconv_main(const float* __restrict__ x,
                             const __hip_bfloat16* __restrict__ xs,
                             const __hip_bfloat16* __restrict__ Wb,
                             const float* __restrict__ Wt0,
                             const float* __restrict__ bp,
                             float* __restrict__ out) {
  __shared__ __align__(16) char smem[49152];  // A dbuf 16K + B dbuf 32K; reused as 32KB zbuf
  __shared__ float tc_lds[128];
  ushort* Ab = (ushort*)smem;                 // 2 x 4096 ushort
  ushort* Bb = (ushort*)(smem + 16384);       // 2 x 8192 ushort
  float* zbuf = (float*)smem;                 // epilogue: 32 rows x 256 f32

  const int tid = threadIdx.x;
  const int w = tid >> 6, lane = tid & 63;
  const int quad = lane >> 4, ln = lane & 15;
  const int pix_base = blockIdx.x * 128;
  const int m_off = (w >> 1) * 64, n_off = (w & 1) * 128;

  // A staging coords: chunk q=0,1 -> pixel = pix_base + q*64 + lane, kgroup = w
  int a_bx[2], a_by[2], a_bb[2];
#pragma unroll
  for (int q = 0; q < 2; ++q) {
    int pix = pix_base + q * 64 + lane;
    a_bx[q] = pix & 63; a_by[q] = (pix >> 6) & 63; a_bb[q] = pix >> 12;
  }
  // B staging source base: chunk p -> n = p*64+lane, kgroup = w
  const __hip_bfloat16* b_src[4];
#pragma unroll
  for (int p = 0; p < 4; ++p)
    b_src[p] = Wb + (size_t)(p * 64 + lane) * 576 + w * 8;

  floatx4 acc[4][8];
#pragma unroll
  for (int mf = 0; mf < 4; ++mf)
#pragma unroll
    for (int nf = 0; nf < 8; ++nf)
      acc[mf][nf] = (floatx4){0.f, 0.f, 0.f, 0.f};

  STAGE(0, 0);  // prologue loads in flight

  // t_cat per block row, from original fp32 x (col 0)
  if (tid < 128) {
    int pix = pix_base + tid;
    int bx = pix & 63, by = (pix >> 6) & 63, bb = pix >> 12;
    float s = 0.f;
#pragma unroll
    for (int dy = -1; dy <= 1; ++dy) {
      int y2 = CLAMP63(by + dy);
#pragma unroll
      for (int dx = -1; dx <= 1; ++dx) {
        int x2 = CLAMP63(bx + dx);
        float t = x[(size_t)((bb * 64 + y2) * 64 + x2) * 65];
        s += t * t;
      }
    }
    tc_lds[tid] = sqrtf(s - 8.0f);
  }

  for (int it = 0; it < 18; ++it) {
    __syncthreads();                 // drains vmcnt -> buf(it&1) ready; prev frag reads done
    if (it < 17) STAGE(it + 1, (it + 1) & 1);   // prefetch overlaps frag reads + MFMA below
    const ushort* Ar = Ab + (it & 1) * 4096;
    const ushort* Br = Bb + (it & 1) * 8192;
    short8 af[4], bfr[8];
#pragma unroll
    for (int mf = 0; mf < 4; ++mf)
      af[mf] = *(const short8*)&Ar[(quad * 128 + m_off + mf * 16 + ln) * 8];
#pragma unroll
    for (int nf = 0; nf < 8; ++nf)
      bfr[nf] = *(const short8*)&Br[(quad * 256 + n_off + nf * 16 + ln) * 8];
#pragma unroll
    for (int mf = 0; mf < 4; ++mf)
#pragma unroll
      for (int nf = 0; nf < 8; ++nf)
        acc[mf][nf] = __builtin_amdgcn_mfma_f32_16x16x32_bf16(af[mf], bfr[nf], acc[mf][nf], 0, 0, 0);
  }

  // ---- epilogue: z = acc + b[n] + t_cat[m]*W0[n]; rows staged in LDS, flushed as 1KB stores
  __syncthreads();
  float wn[8], bnv[8];
#pragma unroll
  for (int nf = 0; nf < 8; ++nf) {
    int n = n_off + nf * 16 + ln;
    wn[nf] = Wt0[n];
    bnv[nf] = bp[n];
  }

#pragma unroll
  for (int mf = 0; mf < 4; ++mf) {
    // stage 32 rows (m = m_off + mf*16 + quad*4 + r) into zbuf; z[n] -> col (1+n)&255
    // (z[255] == 0 by construction: W row 255 / b / Wt0 padding are zero)
#pragma unroll
    for (int r = 0; r < 4; ++r) {
      float tcv = tc_lds[m_off + mf * 16 + quad * 4 + r];
      int lr = (w >> 1) * 16 + quad * 4 + r;
#pragma unroll
      for (int nf = 0; nf < 8; ++nf) {
        float z = acc[mf][nf][r] + bnv[nf] + tcv * wn[nf];
        zbuf[lr * 256 + ((1 + n_off + nf * 16 + ln) & 255)] = z;
      }
    }
    __syncthreads();
    // flush: each wave writes 8 full rows; sum(z^2) via 64-lane butterfly, t_out -> col 0
#pragma unroll
    for (int rr = 0; rr < 8; ++rr) {
      int lr = w * 8 + rr;
      float4 v = *(const float4*)&zbuf[lr * 256 + lane * 4];
      float ss = v.x * v.x + v.y * v.y + v.z * v.z + v.w * v.w;  // col0 holds z[255]=0
      ss += __shfl_xor(ss, 1, 64);
      ss += __shfl_xor(ss, 2, 64);
      ss += __shfl_xor(ss, 4, 64);
      ss += __shfl_xor(ss, 8, 64);
      ss += __shfl_xor(ss, 16, 64);
      ss += __shfl_xor(ss, 32, 64);
      float tout = sqrtf(1.0f + ss);
      if (lane == 0) v.x = tout;
      int m = (lr >> 4) * 64 + mf * 16 + (lr & 15);
      *(float4*)&out[(size_t)(pix_base + m) * 256 + lane * 4] = v;
    }
    if (mf < 3) __syncthreads();  // protect zbuf before next chunk's staging
  }
}

extern "C" void kernel_launch(void* const* d_in, const int* in_sizes, int n_in,
                              void* d_out, int out_size, void* d_ws, size_t ws_size,
                              hipStream_t stream) {
  const float* x = (const float*)d_in[0];   // (32,64,64,65)
  const float* W = (const float*)d_in[1];   // (255,577)
  const float* b = (const float*)d_in[2];   // (255,)
  float* out = (float*)d_out;               // (32,64,64,256)
  char* ws = (char*)d_ws;

  // workspace: xs 16,777,216 B | Wb 294,912 B | Wt0 1KB | bp 1KB   (~17.1 MB)
  __hip_bfloat16* xs  = (__hip_bfloat16*)(ws);
  __hip_bfloat16* Wb  = (__hip_bfloat16*)(ws + 16777216);
  float*          Wt0 = (float*)(ws + 17072128);
  float*          bp  = (float*)(ws + 17073152);

  prep_x<<<4096, 256, 0, stream>>>(x, xs);
  prep_w<<<256,  256, 0, stream>>>(W, b, Wb, Wt0, bp);
  hypconv_main<<<1024, 256, 0, stream>>>(x, xs, Wb, Wt0, bp, out);
}

// Round 5
// 221.858 us; speedup vs baseline: 1.0226x; 1.0134x over previous
//
#include <hip/hip_runtime.h>
#include <hip/hip_bf16.h>

// HypConvHyperboloid: B=32,H=64,W=64, C_IN=65, 3x3 edge-pad conv -> HCat(577) -> Lorentz FC(255) -> time restore
// M = 131072 pixels, K = 576 (bf16 MFMA) + 1 (t_cat fp32 rank-1 in epilogue), N = 255 (pad 256)
// Round 5: 512-thr blocks (8 waves of 64x64 -> acc 64 regs, 2 blocks/CU = 16 waves),
//          tcat from tsq (kills the +16MB strided HBM fetch of r4), zbuf stride 260 (kills 4-way conflicts).

#define CLAMP63(v) ((v) < 0 ? 0 : ((v) > 63 ? 63 : (v)))

typedef __attribute__((ext_vector_type(8))) short short8;   // 8 bf16 = 4 VGPRs
typedef __attribute__((ext_vector_type(4))) float floatx4;  // C/D frag

__device__ __forceinline__ void gl2lds16(const void* g, void* l) {
  __builtin_amdgcn_global_load_lds(
      (const __attribute__((address_space(1))) void*)g,
      (__attribute__((address_space(3))) void*)l, 16, 0, 0);
}

// ---- prep: x spatial -> bf16 pixel-major [pix][64] (16B stores); col0 -> tsq = t^2
__global__ void prep_x(const float* __restrict__ x, __hip_bfloat16* __restrict__ xs,
                       float* __restrict__ tsq) {
  int idx = blockIdx.x * 256 + threadIdx.x;   // 1048576 = 131072 pix * 8 groups
  int p = idx >> 3, g = idx & 7;
  const float* src = x + (size_t)p * 65 + 1 + g * 8;
  __align__(16) __hip_bfloat16 tmp[8];
#pragma unroll
  for (int i = 0; i < 8; ++i) tmp[i] = __float2bfloat16(src[i]);
  *(short8*)(xs + (size_t)idx * 8) = *(const short8*)tmp;
  if (g == 0) { float t = x[(size_t)p * 65]; tsq[p] = t * t; }  // same cacheline as cols 1..8
}

// ---- prep: W spatial cols -> bf16 n-major [256][576] (row 255 zero); W col0 + b -> fp32 padded
__global__ void prep_w(const float* __restrict__ W, const float* __restrict__ b,
                       __hip_bfloat16* __restrict__ Wb, float* __restrict__ Wt0,
                       float* __restrict__ bp) {
  int n = blockIdx.x;  // 256
  for (int k = threadIdx.x; k < 576; k += 256)
    Wb[n * 576 + k] = __float2bfloat16((n < 255) ? W[n * 577 + 1 + k] : 0.f);
  if (threadIdx.x == 0) {
    Wt0[n] = (n < 255) ? W[n * 577] : 0.f;
    bp[n]  = (n < 255) ? b[n] : 0.f;
  }
}

// staging for one iteration (A: 1 chunk/wave, B: 2 chunks/wave; dests wave-uniform)
#define STAGE(IT, BUF)                                                          \
  do {                                                                          \
    const int nbr_ = (IT) >> 1;                                                 \
    const int dy_ = nbr_ / 3 - 1, dx_ = nbr_ % 3 - 1;                           \
    const int c0_ = ((IT) & 1) * 32;                                            \
    int y2_ = CLAMP63(a_by + dy_);                                              \
    int x2_ = CLAMP63(a_bx + dx_);                                              \
    gl2lds16(xs + (size_t)((a_bb * 64 + y2_) * 64 + x2_) * 64 + c0_ + a_kg * 8, \
             Ab + (BUF) * 4096 + w * 512);                                      \
    _Pragma("unroll")                                                           \
    for (int j = 0; j < 2; ++j)                                                 \
      gl2lds16(b_src[j] + (IT) * 32, Bb + (BUF) * 8192 + (w * 2 + j) * 512);    \
  } while (0)

// ---- main: M=128 x N=256 per block, BK=32, 18 iters, 8 waves (each 64x64), dbuf LDS.
// LDS A: slot = kg*128 + m (16B slots); LDS B: slot = kg*256 + n. Frag reads = const + ln*16.
__launch_bounds__(512, 4)
__global__ void hypconv_main(const float* __restrict__ tsq,
                             const __hip_bfloat16* __restrict__ xs,
                             const __hip_bfloat16* __restrict__ Wb,
                             const float* __restrict__ Wt0,
                             const float* __restrict__ bp,
                             float* __restrict__ out) {
  __shared__ __align__(16) char smem[49152];  // A dbuf 16K + B dbuf 32K; reused: zbuf 32 x 260 f32
  __shared__ float tc_lds[128];
  ushort* Ab = (ushort*)smem;                 // 2 x 4096 ushort
  ushort* Bb = (ushort*)(smem + 16384);       // 2 x 8192 ushort
  float* zbuf = (float*)smem;                 // 32 rows x 260 f32 = 33280 B

  const int tid = threadIdx.x;
  const int w = tid >> 6, lane = tid & 63;
  const int quad = lane >> 4, ln = lane & 15;
  const int pix_base = blockIdx.x * 128;
  const int m_off = (w >> 2) * 64, n_off = (w & 3) * 64;

  // A chunk: slot = w*64+lane -> kg = w>>1, m = (w&1)*64+lane
  const int a_kg = w >> 1;
  int apix = pix_base + (w & 1) * 64 + lane;
  const int a_bx = apix & 63, a_by = (apix >> 6) & 63, a_bb = apix >> 12;
  // B chunks j=0,1: slot = (w*2+j)*64+lane -> kg = (w*2+j)>>2, n = ((w*2+j)&3)*64+lane
  const __hip_bfloat16* b_src[2];
#pragma unroll
  for (int j = 0; j < 2; ++j) {
    int c = w * 2 + j;
    b_src[j] = Wb + (size_t)((c & 3) * 64 + lane) * 576 + (c >> 2) * 8;
  }

  floatx4 acc[4][4];
#pragma unroll
  for (int mf = 0; mf < 4; ++mf)
#pragma unroll
    for (int nf = 0; nf < 4; ++nf)
      acc[mf][nf] = (floatx4){0.f, 0.f, 0.f, 0.f};

  STAGE(0, 0);  // prologue loads in flight

  // t_cat from tsq (512 KB, L2-resident; no strided HBM fetch)
  if (tid < 128) {
    int pix = pix_base + tid;
    int bx = pix & 63, by = (pix >> 6) & 63, bb = pix >> 12;
    float s = 0.f;
#pragma unroll
    for (int dy = -1; dy <= 1; ++dy) {
      int y2 = CLAMP63(by + dy);
#pragma unroll
      for (int dx = -1; dx <= 1; ++dx) {
        int x2 = CLAMP63(bx + dx);
        s += tsq[(bb * 64 + y2) * 64 + x2];
      }
    }
    tc_lds[tid] = sqrtf(s - 8.0f);
  }

  for (int it = 0; it < 18; ++it) {
    __syncthreads();                 // buf(it&1) ready; prev frag reads done
    if (it < 17) STAGE(it + 1, (it + 1) & 1);   // prefetch overlaps frag reads + MFMA
    const ushort* Ar = Ab + (it & 1) * 4096;
    const ushort* Br = Bb + (it & 1) * 8192;
    short8 af[4], bfr[4];
#pragma unroll
    for (int mf = 0; mf < 4; ++mf)
      af[mf] = *(const short8*)&Ar[(quad * 128 + m_off + mf * 16 + ln) * 8];
#pragma unroll
    for (int nf = 0; nf < 4; ++nf)
      bfr[nf] = *(const short8*)&Br[(quad * 256 + n_off + nf * 16 + ln) * 8];
#pragma unroll
    for (int mf = 0; mf < 4; ++mf)
#pragma unroll
      for (int nf = 0; nf < 4; ++nf)
        acc[mf][nf] = __builtin_amdgcn_mfma_f32_16x16x32_bf16(af[mf], bfr[nf], acc[mf][nf], 0, 0, 0);
  }

  // ---- epilogue: z = acc + b[n] + t_cat[m]*W0[n]; LDS-staged (stride 260), 1KB-row flush
  __syncthreads();
  float wn[4], bnv[4];
#pragma unroll
  for (int nf = 0; nf < 4; ++nf) {
    int n = n_off + nf * 16 + ln;
    wn[nf] = Wt0[n];
    bnv[nf] = bp[n];
  }

#pragma unroll
  for (int mf = 0; mf < 4; ++mf) {
    // stage 32 rows: lr = (w>>2)*16 + quad*4 + r ; col = (1+n)&255 (z[255]=0 by padding)
#pragma unroll
    for (int r = 0; r < 4; ++r) {
      float tcv = tc_lds[m_off + mf * 16 + quad * 4 + r];
      int lr = (w >> 2) * 16 + quad * 4 + r;
#pragma unroll
      for (int nf = 0; nf < 4; ++nf) {
        float z = acc[mf][nf][r] + bnv[nf] + tcv * wn[nf];
        zbuf[lr * 260 + ((1 + n_off + nf * 16 + ln) & 255)] = z;
      }
    }
    __syncthreads();
    // flush: 8 waves x 4 rows; sum(z^2) 64-lane butterfly; t_out -> col 0
#pragma unroll
    for (int rr = 0; rr < 4; ++rr) {
      int lr = w * 4 + rr;
      float4 v = *(const float4*)&zbuf[lr * 260 + lane * 4];
      float ss = v.x * v.x + v.y * v.y + v.z * v.z + v.w * v.w;  // col0 holds z[255]=0
      ss += __shfl_xor(ss, 1, 64);
      ss += __shfl_xor(ss, 2, 64);
      ss += __shfl_xor(ss, 4, 64);
      ss += __shfl_xor(ss, 8, 64);
      ss += __shfl_xor(ss, 16, 64);
      ss += __shfl_xor(ss, 32, 64);
      float tout = sqrtf(1.0f + ss);
      if (lane == 0) v.x = tout;
      int m = (lr >> 4) * 64 + mf * 16 + (lr & 15);
      *(float4*)&out[(size_t)(pix_base + m) * 256 + lane * 4] = v;
    }
    if (mf < 3) __syncthreads();  // protect zbuf before next chunk's staging
  }
}

extern "C" void kernel_launch(void* const* d_in, const int* in_sizes, int n_in,
                              void* d_out, int out_size, void* d_ws, size_t ws_size,
                              hipStream_t stream) {
  const float* x = (const float*)d_in[0];   // (32,64,64,65)
  const float* W = (const float*)d_in[1];   // (255,577)
  const float* b = (const float*)d_in[2];   // (255,)
  float* out = (float*)d_out;               // (32,64,64,256)
  char* ws = (char*)d_ws;

  // workspace: xs 16,777,216 | Wb 294,912 | Wt0 1K | bp 1K | tsq 524,288  (~17.6 MB)
  __hip_bfloat16* xs  = (__hip_bfloat16*)(ws);
  __hip_bfloat16* Wb  = (__hip_bfloat16*)(ws + 16777216);
  float*          Wt0 = (float*)(ws + 17072128);
  float*          bp  = (float*)(ws + 17073152);
  float*          tsq = (float*)(ws + 17074176);

  prep_x<<<4096, 256, 0, stream>>>(x, xs, tsq);
  prep_w<<<256,  256, 0, stream>>>(W, b, Wb, Wt0, bp);
  hypconv_main<<<1024, 512, 0, stream>>>(tsq, xs, Wb, Wt0, bp, out);
}